// Round 5
// baseline (596.329 us; speedup 1.0000x reference)
//
#include <hip/hip_runtime.h>
#include <hip/hip_bf16.h>
#include <cmath>

typedef unsigned short u16;
typedef unsigned int   u32;

using v4f    = __attribute__((ext_vector_type(4)))  float;
using f32x16 = __attribute__((ext_vector_type(16))) float;
using s8v    = __attribute__((ext_vector_type(8)))  short;
using u32x2  = __attribute__((ext_vector_type(2)))  unsigned int;

union Frag { uint4 u; s8v s; };

__device__ __forceinline__ u16 f2bf(float f){
  u32 u = __float_as_uint(f);
  u32 r = u + 0x7fffu + ((u >> 16) & 1u);
  return (u16)(r >> 16);
}
__device__ __forceinline__ float bf2f(u16 h){ return __uint_as_float(((u32)h) << 16); }

// pack two f32 -> one dword of 2 bf16 (RNE), single VALU op (T12 recipe; no builtin on gfx950)
__device__ __forceinline__ u32 cvtpk(float a, float b){
  u32 r;
  asm("v_cvt_pk_bf16_f32 %0, %1, %2" : "=v"(r) : "v"(a), "v"(b));
  return r;
}

// async global->LDS, 16B per lane; LDS dest is wave-uniform base + lane*16
__device__ __forceinline__ void async16(const void* g, void* l){
  __builtin_amdgcn_global_load_lds((__attribute__((address_space(1))) void*)g,
                                   (__attribute__((address_space(3))) void*)l, 16, 0, 0);
}

// ---------------- cast x (fp32 -> bf16) ----------------
__global__ __launch_bounds__(256) void cast_x_kernel(const float* __restrict__ x, u16* __restrict__ xb){
  size_t i = ((size_t)blockIdx.x * 256 + threadIdx.x) * 4;
  float4 v = *(const float4*)(x + i);
  uint2 o;
  o.x = (u32)f2bf(v.x) | ((u32)f2bf(v.y) << 16);
  o.y = (u32)f2bf(v.z) | ((u32)f2bf(v.w) << 16);
  *(uint2*)(xb + i) = o;
}

// ---------------- cast + transpose weights: W[k][n] fp32 -> WT[n][k] bf16 ----------------
__global__ __launch_bounds__(256) void cast_transpose_kernel(
    const float* __restrict__ W0, const float* __restrict__ W1,
    const float* __restrict__ W2, const float* __restrict__ W3,
    u16* __restrict__ T0, u16* __restrict__ T1, u16* __restrict__ T2, u16* __restrict__ T3){
  __shared__ float tile[64][65];
  const float* W = (blockIdx.z==0)?W0:(blockIdx.z==1)?W1:(blockIdx.z==2)?W2:W3;
  u16*         T = (blockIdx.z==0)?T0:(blockIdx.z==1)?T1:(blockIdx.z==2)?T2:T3;
  const int k0 = blockIdx.y*64, n0 = blockIdx.x*64;
  const int t  = threadIdx.x;
  const int rr = t >> 4, c4 = (t & 15) * 4;
  #pragma unroll
  for (int i=0;i<4;i++){
    int k = rr + i*16;
    float4 v = *(const float4*)(W + (size_t)(k0+k)*2048 + n0 + c4);
    tile[k][c4+0]=v.x; tile[k][c4+1]=v.y; tile[k][c4+2]=v.z; tile[k][c4+3]=v.w;
  }
  __syncthreads();
  #pragma unroll
  for (int i=0;i<4;i++){
    int n = rr + i*16;
    uint2 o;
    o.x = (u32)f2bf(tile[c4+0][n]) | ((u32)f2bf(tile[c4+1][n])<<16);
    o.y = (u32)f2bf(tile[c4+2][n]) | ((u32)f2bf(tile[c4+3][n])<<16);
    *(uint2*)(T + (size_t)(n0+n)*2048 + k0 + c4) = o;
  }
}

// ---------------- bf16 MFMA GEMM core (m97-style) ----------------
// C[128x128 tile] = A[m0..+128][kbeg..kend) * BT[n0..+128][kbeg..kend)^T (+ bias). LDS tiles
// 128x64 u16, unpadded, 16B-block XOR swizzle: data block b of row r stored at pos b^(r&7).
// MODE 0: bf16 out + bias. MODE 1: fp32 out + bias. MODE 2: fp32 partial, no bias.
template<int MODE>
__device__ __forceinline__ void gemm_tile(const u16* __restrict__ A, const u16* __restrict__ BT,
                                          const float* __restrict__ bias, void* __restrict__ Cout,
                                          int m0, int n0, int kbeg, int kend, u16* Asl, u16* Bsl){
  constexpr int K = 2048;
  const int tid  = threadIdx.x;
  const int w    = tid >> 6;
  const int lane = tid & 63;
  const int r    = lane & 15, q = lane >> 4;
  const int wm   = (w >> 1) * 64, wn = (w & 1) * 64;

  v4f acc[4][4];
  #pragma unroll
  for (int i=0;i<4;i++)
    #pragma unroll
    for (int j=0;j<4;j++) acc[i][j] = (v4f)0.f;

  // staging geometry: per instr 8 rows x 8 blocks; wave w covers rows [w*32, w*32+32)
  const int srow = w*32 + (lane>>3);
  const int sblk = (lane&7) ^ ((lane>>3)&7);   // swizzled source block for this lane's LDS slot
  const u16* Ag = A  + (size_t)(m0+srow)*K + sblk*8;
  const u16* Bg = BT + (size_t)(n0+srow)*K + sblk*8;
  u16* Als = Asl + (w*32)*64;
  u16* Bls = Bsl + (w*32)*64;

  for (int kk = kbeg; kk < kend; kk += 64) {
    #pragma unroll
    for (int i=0;i<4;i++){
      async16(Ag + (size_t)i*8*K + kk, Als + i*512);
      async16(Bg + (size_t)i*8*K + kk, Bls + i*512);
    }
    __syncthreads();
    #pragma unroll
    for (int ks=0; ks<2; ++ks) {
      s8v af[4], bfr[4];
      #pragma unroll
      for (int i=0;i<4;i++){
        int rho = wm + i*16 + r;
        int p = (ks*4 + q) ^ (r&7);
        Frag t; t.u = *(const uint4*)(Asl + rho*64 + p*8); af[i] = t.s;
      }
      #pragma unroll
      for (int j=0;j<4;j++){
        int rho = wn + j*16 + r;
        int p = (ks*4 + q) ^ (r&7);
        Frag t; t.u = *(const uint4*)(Bsl + rho*64 + p*8); bfr[j] = t.s;
      }
      #pragma unroll
      for (int i=0;i<4;i++)
        #pragma unroll
        for (int j=0;j<4;j++)
          acc[i][j] = __builtin_amdgcn_mfma_f32_16x16x32_bf16(af[i], bfr[j], acc[i][j], 0, 0, 0);
    }
    __syncthreads();
  }

  float bv[4];
  if constexpr (MODE < 2){
    #pragma unroll
    for (int j=0;j<4;j++) bv[j] = bias[n0 + wn + j*16 + r];
  } else {
    #pragma unroll
    for (int j=0;j<4;j++) bv[j] = 0.f;
  }

  #pragma unroll
  for (int i=0;i<4;i++){
    #pragma unroll
    for (int j=0;j<4;j++){
      const int gn = n0 + wn + j*16 + r;
      #pragma unroll
      for (int rr2=0; rr2<4; ++rr2){
        const int gm = m0 + wm + i*16 + q*4 + rr2;
        float val = acc[i][j][rr2] + bv[j];
        if (MODE == 0) ((u16*)Cout)[(size_t)gm*2048 + gn] = f2bf(val);
        else           ((float*)Cout)[(size_t)gm*2048 + gn] = val;
      }
    }
  }
}

// fused Q/K/V projection: one grid of 48x32 tiles -> cross-block overlap hides the
// per-K-step barrier drain that 512-block single-GEMM launches exposed. 873 TF measured.
__global__ __launch_bounds__(256) void gemm_qkv_kernel(
    const u16* __restrict__ A,
    const u16* __restrict__ WqT, const u16* __restrict__ WkT, const u16* __restrict__ WvT,
    const float* __restrict__ bq, const float* __restrict__ bk, const float* __restrict__ bv,
    u16* __restrict__ Qb, u16* __restrict__ Kb, u16* __restrict__ Vb){
  __shared__ u16 Asl[128*64];
  __shared__ u16 Bsl[128*64];
  const int mat = blockIdx.x >> 4;                 // 0:Q 1:K 2:V
  const u16*   BT   = (mat==0)?WqT:(mat==1)?WkT:WvT;
  const float* bias = (mat==0)?bq :(mat==1)?bk :bv;
  u16*         Cout = (mat==0)?Qb :(mat==1)?Kb :Vb;
  gemm_tile<0>(A, BT, bias, Cout, blockIdx.y*128, (blockIdx.x & 15)*128, 0, 2048, Asl, Bsl);
}

// Wo projection, split-K2: z in {0,1} computes K-half into fp32 partial -> 1024 blocks (4/CU)
__global__ __launch_bounds__(256) void gemm_wo_kernel(const u16* __restrict__ A,
                                                      const u16* __restrict__ WoT,
                                                      float* __restrict__ part){
  __shared__ u16 Asl[128*64];
  __shared__ u16 Bsl[128*64];
  const int z = blockIdx.z;
  gemm_tile<2>(A, WoT, nullptr, part + (size_t)z*8388608,
               blockIdx.y*128, blockIdx.x*128, z*1024, z*1024+1024, Asl, Bsl);
}

// out = p0 + p1 + bias (row-major [4096][2048] fp32)
__global__ __launch_bounds__(256) void add_bias_kernel(const float* __restrict__ p0,
                                                       const float* __restrict__ p1,
                                                       const float* __restrict__ bias,
                                                       float* __restrict__ out){
  size_t i = ((size_t)blockIdx.x * 256 + threadIdx.x) * 4;
  float4 a = *(const float4*)(p0 + i);
  float4 b = *(const float4*)(p1 + i);
  float4 c = *(const float4*)(bias + (i & 2047));
  float4 o; o.x = a.x+b.x+c.x; o.y = a.y+b.y+c.y; o.z = a.z+b.z+c.z; o.w = a.w+b.w+c.w;
  *(float4*)(out + i) = o;
}

// ---------------- RoPE in place on bf16 [B,S,H,D], one wave per (b,s,h) row ----------------
__global__ __launch_bounds__(256) void rope_kernel(u16* __restrict__ Q, u16* __restrict__ Kb){
  const int wrow = blockIdx.x*4 + (threadIdx.x >> 6);  // 0 .. 65535 over (b,s,h)
  const int lane = threadIdx.x & 63;
  u16* P = (blockIdx.y == 0) ? Q : Kb;
  const int s = (wrow >> 4) & 2047;
  const size_t base = (size_t)wrow * 128;
  float invf = exp2f(-(float)lane * 0.20762050593045952f);  // log2(10000)/64
  float angle = (float)s * invf;
  float sn, cs;
  sincosf(angle, &sn, &cs);
  float x_j   = bf2f(P[base + lane]);
  float x_j64 = bf2f(P[base + 64 + lane]);
  float x_2j  = bf2f(P[base + 2*lane]);
  float x_2j1 = bf2f(P[base + 2*lane + 1]);
  float o0 = x_j  * cs - x_2j1 * sn;
  float o1 = x_j64 * cs + x_2j  * sn;
  P[base + lane]      = f2bf(o0);
  P[base + 64 + lane] = f2bf(o1);
}

// ---------------- transpose V: [B,S,H,D] -> VT [B,H,D,S] ----------------
__global__ __launch_bounds__(256) void transpose_v_kernel(const u16* __restrict__ V, u16* __restrict__ VT){
  __shared__ u16 t[64*72];
  const int s0 = blockIdx.x*64;
  const int d0 = blockIdx.y*64;
  const int bh = blockIdx.z;
  const int b = bh >> 4, h = bh & 15;
  const size_t obase = ((size_t)bh*128 + d0)*2048 + s0;
  const int tid = threadIdx.x;
  #pragma unroll
  for (int i=0;i<2;i++){
    int c = tid + i*256;
    int sl = c >> 3, dc = (c & 7) * 8;
    *(uint4*)(t + sl*72 + dc) =
      *(const uint4*)(V + ((size_t)(b*2048 + s0 + sl))*2048 + h*128 + d0 + dc);
  }
  __syncthreads();
  #pragma unroll
  for (int i=0;i<2;i++){
    int c = tid + i*256;
    int dl = c >> 3, sc4 = (c & 7) * 8;
    u16 tmp[8];
    #pragma unroll
    for (int j=0;j<8;j++) tmp[j] = t[(sc4+j)*72 + dl];
    *(uint4*)(VT + obase + (size_t)dl*2048 + sc4) = *(const uint4*)tmp;
  }
}

// ---------------- flash attention v5: 8-wave key-split ----------------
// 512 threads = 8 waves. Waves w&3 own q-rows [q0 + (w&3)*32, +32); group grp=w>>2 handles
// key-half [grp*32, grp*32+32) of every 64-key tile. Same shared dbuf K/V tiles as v3/v4
// (64KB LDS -> 2 blocks/CU -> 16 waves/CU = 4 waves/SIMD, 2x the residency of the 4-wave
// version whose 2 waves/SIMD left a ~5x latency gap). No-max softmax => cross-group merge
// is a pure sum of (O, l), done through LDS at the end.
__global__ __launch_bounds__(512,4) void attn_kernel(const u16* __restrict__ Q,
                                                     const u16* __restrict__ K,
                                                     const u16* __restrict__ VT,
                                                     const int* __restrict__ mask,
                                                     u16* __restrict__ Out){
  constexpr int S = 2048;
  constexpr float SL2 = 0.08838834764831845f * 1.4426950408889634f;  // 1/sqrt(128) * log2(e)
  __shared__ u16 smem[32768];          // 64 KB: two 32KB buffers {K [64][128], V [128][64]}

  const int tid = threadIdx.x, w = tid >> 6, lane = tid & 63;
  const int wg  = w & 3;               // q-row group
  const int grp = w >> 2;              // key-half group
  const int qc = lane & 31;            // owned q-row; also key-row / d-row for A-frag reads
  const int h  = lane >> 5;            // k-slice half (A/B frag: k = 8*h + j)
  const int l7 = lane & 7;
  const int hh = blockIdx.y, b = blockIdx.z;
  const int q0 = blockIdx.x * 128;
  const size_t rowb = (size_t)b * 2048;
  const size_t bhD  = ((size_t)(b*16 + hh)) * 128;

  // Q fragments (B-operand: col = q = qc, k = d = 16t + 8h + j) straight from global (read once)
  s8v qf[8];
  {
    const u16* qp = Q + (rowb + q0 + wg*32 + qc)*2048 + hh*128 + h*8;
    #pragma unroll
    for (int t=0;t<8;t++){ Frag f; f.u = *(const uint4*)(qp + t*16); qf[t] = f.s; }
  }

  f32x16 accO[4];                      // O^T: [d-block][16 regs]; row=d local, col=q=qc
  #pragma unroll
  for (int d=0; d<4; d++) accO[d] = (f32x16)0.f;
  float lsum = 0.f;

  const int sr4 = lane >> 4, sp16 = lane & 15;   // K staging: 4 rows x 16 blocks per instr
  const int vr8 = lane >> 3, vp8 = lane & 7;     // V staging: 8 rows x 8 blocks per instr

  // stage K tile [64][128] + V tile [128][64]; 8 waves, 2+2 instrs each
  auto stage = [&](u16* base, int key0){
    u16* Kd = base;
    u16* Vd = base + 8192;
    #pragma unroll
    for (int i=0;i<2;i++){
      int R = w*8 + i*4;                          // K rows [w*8, w*8+8)
      int ob = sp16 ^ ((R&7) + sr4);              // (R+sr4)&7: R&7 in {0,4}, sr4<4
      async16(K + (rowb + key0 + R + sr4)*2048 + hh*128 + ob*8, Kd + R*128);
    }
    #pragma unroll
    for (int i=0;i<2;i++){
      int R = w*16 + i*8;                         // V d-rows [w*16, w*16+16)
      int ob = vp8 ^ vr8;                         // (R&7)==0
      async16(VT + (bhD + R + vr8)*2048 + key0 + ob*8, Vd + R*64);
    }
  };

  // ---- prologue: stage tile 0, mask row 0 ----
  stage(smem, 0);
  int mv = mask[b*S + lane];
  __syncthreads();                                 // drains vmcnt -> buf0 ready
  unsigned long long bm = __ballot(mv != 0);
  int cur = 0;

  for (int it=0; it<32; ++it){
    // ---- issue next tile's loads before compute (2-phase pipeline) ----
    if (it < 31){
      stage(smem + (cur^1)*16384, (it+1)*64);
      mv = mask[b*S + (it+1)*64 + lane];
    }
    const u16* Ks = smem + cur*16384;              // [64 keys][128 d]
    const u16* Vs = Ks + 8192;                     // [128 d][64 keys]

    // ---- S^T[key=grp*32+..][q] = K Q^T (this group's 32 keys) ----
    f32x16 sc = (f32x16)0.f;
    __builtin_amdgcn_s_setprio(1);
    #pragma unroll
    for (int t=0;t<8;t++){
      Frag kf; kf.u = *(const uint4*)(Ks + (grp*32 + qc)*128 + (((2*t + h) ^ l7)*8));
      sc = __builtin_amdgcn_mfma_f32_32x32x16_bf16(kf.s, qf[t], sc, 0, 0, 0);
    }
    __builtin_amdgcn_s_setprio(0);
    // ---- P = exp(score/sqrt(d)) (no-max softmax), lane-local row sum ----
    float p[16];
    #pragma unroll
    for (int m=0; m<16; ++m) p[m] = exp2f(sc[m] * SL2);
    if (bm != ~0ull){                              // wave-uniform fast path: mask all valid
      #pragma unroll
      for (int m=0; m<16; ++m){
        int bit = grp*32 + (m&3) + 8*(m>>2) + 4*h;
        if (!((bm >> bit) & 1ull)) p[m] = 0.f;
      }
    }
    #pragma unroll
    for (int m=0; m<16; ++m) lsum += p[m];

    // ---- build P^T B-frags in-register and do PV ----
    #pragma unroll
    for (int gi=0; gi<2; ++gi){                    // 16-key sub-tile -> one frag
      u32 a0 = cvtpk(p[8*gi+0], p[8*gi+1]);        // keys 4h+{0,1}   (+16gi local)
      u32 a1 = cvtpk(p[8*gi+2], p[8*gi+3]);        // keys 4h+{2,3}
      u32 a2 = cvtpk(p[8*gi+4], p[8*gi+5]);        // keys 8+4h+{0,1}
      u32 a3 = cvtpk(p[8*gi+6], p[8*gi+7]);        // keys 8+4h+{2,3}
      u32x2 r0 = __builtin_amdgcn_permlane32_swap(a0, a2, false, false);
      u32x2 r1 = __builtin_amdgcn_permlane32_swap(a1, a3, false, false);
      // frag elems j=0..7 = P[qc][16T + 8h + j]  (T indexes the tile's four 16-key slices)
      Frag pf; pf.u = make_uint4(r0[0], r1[0], r0[1], r1[1]);
      const int T = grp*2 + gi;
      __builtin_amdgcn_s_setprio(1);
      #pragma unroll
      for (int d=0; d<4; ++d){
        Frag vf; vf.u = *(const uint4*)(Vs + (d*32 + qc)*64 + (((2*T + h) ^ l7)*8));
        accO[d] = __builtin_amdgcn_mfma_f32_32x32x16_bf16(vf.s, pf.s, accO[d], 0, 0, 0);
      }
      __builtin_amdgcn_s_setprio(0);
    }
    __syncthreads();                               // all waves done with buf[cur]; buf[cur^1] staged
    bm = __ballot(mv != 0);
    cur ^= 1;
  }

  // ---- merge the two key-half groups: l and O are pure sums (no-max softmax) ----
  float sg = lsum + __shfl_xor(lsum, 32, 64);      // this group's row sum (both h halves)
  float* red = (float*)smem;
  __syncthreads();                                 // done with K/V buffers
  if (grp == 1) red[wg*64 + lane] = sg;
  __syncthreads();
  float invv = 0.f;
  if (grp == 0){
    float tot = sg + red[wg*64 + lane];
    invv = (tot > 0.f) ? 1.f/tot : 0.f;
  }
  __syncthreads();
  if (grp == 1){                                   // ship accO: [elem][lane] layout, conflict-free
    float* dst = red + wg*4096;
    #pragma unroll
    for (int d=0; d<4; ++d)
      #pragma unroll
      for (int j=0; j<16; ++j) dst[(d*16+j)*64 + lane] = accO[d][j];
  }
  __syncthreads();
  if (grp == 0){
    const float* src = red + wg*4096;
    #pragma unroll
    for (int d=0; d<4; ++d)
      #pragma unroll
      for (int j=0; j<16; ++j) accO[d][j] += src[(d*16+j)*64 + lane];

    u16* orow = Out + (rowb + q0 + wg*32 + qc)*2048 + hh*128;
    #pragma unroll
    for (int d=0; d<4; ++d){
      #pragma unroll
      for (int g2=0; g2<4; ++g2){
        uint2 o;
        o.x = cvtpk(accO[d][g2*4+0] * invv, accO[d][g2*4+1] * invv);
        o.y = cvtpk(accO[d][g2*4+2] * invv, accO[d][g2*4+3] * invv);
        *(uint2*)(orow + d*32 + g2*8 + 4*h) = o;   // d_local = (reg&3)+8*(reg>>2)+4h
      }
    }
  }
}

extern "C" void kernel_launch(void* const* d_in, const int* in_sizes, int n_in,
                              void* d_out, int out_size, void* d_ws, size_t ws_size,
                              hipStream_t stream) {
  (void)in_sizes; (void)n_in; (void)out_size; (void)ws_size;
  const float* x    = (const float*)d_in[0];
  const int*   mask = (const int*)d_in[1];
  const float* Wq   = (const float*)d_in[2];
  const float* bq   = (const float*)d_in[3];
  const float* Wk   = (const float*)d_in[4];
  const float* bk   = (const float*)d_in[5];
  const float* Wv   = (const float*)d_in[6];
  const float* bv   = (const float*)d_in[7];
  const float* Wo   = (const float*)d_in[8];
  const float* bo   = (const float*)d_in[9];

  u16* xbf = (u16*)d_ws;                 // 8388608 elems
  u16* WqT = xbf + 8388608;              // 4194304 each
  u16* WkT = WqT + 4194304;
  u16* WvT = WkT + 4194304;
  u16* WoT = WvT + 4194304;
  u16* Qb  = WoT + 4194304;              // 8388608 each, [B,S,H,D] row-major
  u16* Kb  = Qb + 8388608;
  u16* Vb  = Kb + 8388608;
  u16* VTb = Vb + 8388608;               // V transposed [B,H,D,S]
  u16* Ab  = VTb + 8388608;              // attn out bf16 [B,S,E]
  // after attn, Qb/Kb/Vb/VTb are dead -> reuse as fp32 split-K partials for the Wo GEMM
  float* part = (float*)Qb;              // part0 = Qb..Kb (8388608 f32), part1 = Vb..VTb

  cast_x_kernel<<<8192, 256, 0, stream>>>(x, xbf);
  cast_transpose_kernel<<<dim3(32,32,4), 256, 0, stream>>>(Wq, Wk, Wv, Wo, WqT, WkT, WvT, WoT);
  gemm_qkv_kernel<<<dim3(48,32), 256, 0, stream>>>(xbf, WqT, WkT, WvT, bq, bk, bv, Qb, Kb, Vb);
  rope_kernel<<<dim3(16384,2), 256, 0, stream>>>(Qb, Kb);
  transpose_v_kernel<<<dim3(32,2,32), 256, 0, stream>>>(Vb, VTb);
  attn_kernel<<<dim3(16,16,2), 512, 0, stream>>>(Qb, Kb, VTb, mask, Ab);
  gemm_wo_kernel<<<dim3(16,32,2), 256, 0, stream>>>(Ab, WoT, part);
  add_bias_kernel<<<8192, 256, 0, stream>>>(part, part + 8388608, bo, (float*)d_out);
}

// Round 6
// 479.028 us; speedup vs baseline: 1.2449x; 1.2449x over previous
//
#include <hip/hip_runtime.h>
#include <hip/hip_bf16.h>
#include <cmath>

typedef unsigned short u16;
typedef unsigned int   u32;

using v4f    = __attribute__((ext_vector_type(4)))  float;
using f32x16 = __attribute__((ext_vector_type(16))) float;
using s8v    = __attribute__((ext_vector_type(8)))  short;
using u32x2  = __attribute__((ext_vector_type(2)))  unsigned int;

union Frag { uint4 u; s8v s; };

__device__ __forceinline__ u16 f2bf(float f){
  u32 u = __float_as_uint(f);
  u32 r = u + 0x7fffu + ((u >> 16) & 1u);
  return (u16)(r >> 16);
}
__device__ __forceinline__ float bf2f(u16 h){ return __uint_as_float(((u32)h) << 16); }

// pack two f32 -> one dword of 2 bf16 (RNE), single VALU op (T12 recipe; no builtin on gfx950)
__device__ __forceinline__ u32 cvtpk(float a, float b){
  u32 r;
  asm("v_cvt_pk_bf16_f32 %0, %1, %2" : "=v"(r) : "v"(a), "v"(b));
  return r;
}

// async global->LDS, 16B per lane; LDS dest is wave-uniform base + lane*16
__device__ __forceinline__ void async16(const void* g, void* l){
  __builtin_amdgcn_global_load_lds((__attribute__((address_space(1))) void*)g,
                                   (__attribute__((address_space(3))) void*)l, 16, 0, 0);
}

// ---------------- cast x (fp32 -> bf16) ----------------
__global__ __launch_bounds__(256) void cast_x_kernel(const float* __restrict__ x, u16* __restrict__ xb){
  size_t i = ((size_t)blockIdx.x * 256 + threadIdx.x) * 4;
  float4 v = *(const float4*)(x + i);
  uint2 o;
  o.x = (u32)f2bf(v.x) | ((u32)f2bf(v.y) << 16);
  o.y = (u32)f2bf(v.z) | ((u32)f2bf(v.w) << 16);
  *(uint2*)(xb + i) = o;
}

// ---------------- cast + transpose weights: W[k][n] fp32 -> WT[n][k] bf16 ----------------
__global__ __launch_bounds__(256) void cast_transpose_kernel(
    const float* __restrict__ W0, const float* __restrict__ W1,
    const float* __restrict__ W2, const float* __restrict__ W3,
    u16* __restrict__ T0, u16* __restrict__ T1, u16* __restrict__ T2, u16* __restrict__ T3){
  __shared__ float tile[64][65];
  const float* W = (blockIdx.z==0)?W0:(blockIdx.z==1)?W1:(blockIdx.z==2)?W2:W3;
  u16*         T = (blockIdx.z==0)?T0:(blockIdx.z==1)?T1:(blockIdx.z==2)?T2:T3;
  const int k0 = blockIdx.y*64, n0 = blockIdx.x*64;
  const int t  = threadIdx.x;
  const int rr = t >> 4, c4 = (t & 15) * 4;
  #pragma unroll
  for (int i=0;i<4;i++){
    int k = rr + i*16;
    float4 v = *(const float4*)(W + (size_t)(k0+k)*2048 + n0 + c4);
    tile[k][c4+0]=v.x; tile[k][c4+1]=v.y; tile[k][c4+2]=v.z; tile[k][c4+3]=v.w;
  }
  __syncthreads();
  #pragma unroll
  for (int i=0;i<4;i++){
    int n = rr + i*16;
    uint2 o;
    o.x = (u32)f2bf(tile[c4+0][n]) | ((u32)f2bf(tile[c4+1][n])<<16);
    o.y = (u32)f2bf(tile[c4+2][n]) | ((u32)f2bf(tile[c4+3][n])<<16);
    *(uint2*)(T + (size_t)(n0+n)*2048 + k0 + c4) = o;
  }
}

// ---------------- bf16 MFMA GEMM core (m97-style) ----------------
// C[128x128 tile] = A[m0..+128][kbeg..kend) * BT[n0..+128][kbeg..kend)^T (+ bias). LDS tiles
// 128x64 u16, unpadded, 16B-block XOR swizzle: data block b of row r stored at pos b^(r&7).
// MODE 0: bf16 out + bias. MODE 1: fp32 out + bias. MODE 2: fp32 partial, no bias.
template<int MODE>
__device__ __forceinline__ void gemm_tile(const u16* __restrict__ A, const u16* __restrict__ BT,
                                          const float* __restrict__ bias, void* __restrict__ Cout,
                                          int m0, int n0, int kbeg, int kend, u16* Asl, u16* Bsl){
  constexpr int K = 2048;
  const int tid  = threadIdx.x;
  const int w    = tid >> 6;
  const int lane = tid & 63;
  const int r    = lane & 15, q = lane >> 4;
  const int wm   = (w >> 1) * 64, wn = (w & 1) * 64;

  v4f acc[4][4];
  #pragma unroll
  for (int i=0;i<4;i++)
    #pragma unroll
    for (int j=0;j<4;j++) acc[i][j] = (v4f)0.f;

  // staging geometry: per instr 8 rows x 8 blocks; wave w covers rows [w*32, w*32+32)
  const int srow = w*32 + (lane>>3);
  const int sblk = (lane&7) ^ ((lane>>3)&7);   // swizzled source block for this lane's LDS slot
  const u16* Ag = A  + (size_t)(m0+srow)*K + sblk*8;
  const u16* Bg = BT + (size_t)(n0+srow)*K + sblk*8;
  u16* Als = Asl + (w*32)*64;
  u16* Bls = Bsl + (w*32)*64;

  for (int kk = kbeg; kk < kend; kk += 64) {
    #pragma unroll
    for (int i=0;i<4;i++){
      async16(Ag + (size_t)i*8*K + kk, Als + i*512);
      async16(Bg + (size_t)i*8*K + kk, Bls + i*512);
    }
    __syncthreads();
    #pragma unroll
    for (int ks=0; ks<2; ++ks) {
      s8v af[4], bfr[4];
      #pragma unroll
      for (int i=0;i<4;i++){
        int rho = wm + i*16 + r;
        int p = (ks*4 + q) ^ (r&7);
        Frag t; t.u = *(const uint4*)(Asl + rho*64 + p*8); af[i] = t.s;
      }
      #pragma unroll
      for (int j=0;j<4;j++){
        int rho = wn + j*16 + r;
        int p = (ks*4 + q) ^ (r&7);
        Frag t; t.u = *(const uint4*)(Bsl + rho*64 + p*8); bfr[j] = t.s;
      }
      #pragma unroll
      for (int i=0;i<4;i++)
        #pragma unroll
        for (int j=0;j<4;j++)
          acc[i][j] = __builtin_amdgcn_mfma_f32_16x16x32_bf16(af[i], bfr[j], acc[i][j], 0, 0, 0);
    }
    __syncthreads();
  }

  float bv[4];
  if constexpr (MODE < 2){
    #pragma unroll
    for (int j=0;j<4;j++) bv[j] = bias[n0 + wn + j*16 + r];
  } else {
    #pragma unroll
    for (int j=0;j<4;j++) bv[j] = 0.f;
  }

  #pragma unroll
  for (int i=0;i<4;i++){
    #pragma unroll
    for (int j=0;j<4;j++){
      const int gn = n0 + wn + j*16 + r;
      #pragma unroll
      for (int rr2=0; rr2<4; ++rr2){
        const int gm = m0 + wm + i*16 + q*4 + rr2;
        float val = acc[i][j][rr2] + bv[j];
        if (MODE == 0) ((u16*)Cout)[(size_t)gm*2048 + gn] = f2bf(val);
        else           ((float*)Cout)[(size_t)gm*2048 + gn] = val;
      }
    }
  }
}

// fused Q/K/V projection: one grid of 48x32 tiles -> cross-block overlap hides the
// per-K-step barrier drain that 512-block single-GEMM launches exposed. 873 TF measured.
__global__ __launch_bounds__(256) void gemm_qkv_kernel(
    const u16* __restrict__ A,
    const u16* __restrict__ WqT, const u16* __restrict__ WkT, const u16* __restrict__ WvT,
    const float* __restrict__ bq, const float* __restrict__ bk, const float* __restrict__ bv,
    u16* __restrict__ Qb, u16* __restrict__ Kb, u16* __restrict__ Vb){
  __shared__ u16 Asl[128*64];
  __shared__ u16 Bsl[128*64];
  const int mat = blockIdx.x >> 4;                 // 0:Q 1:K 2:V
  const u16*   BT   = (mat==0)?WqT:(mat==1)?WkT:WvT;
  const float* bias = (mat==0)?bq :(mat==1)?bk :bv;
  u16*         Cout = (mat==0)?Qb :(mat==1)?Kb :Vb;
  gemm_tile<0>(A, BT, bias, Cout, blockIdx.y*128, (blockIdx.x & 15)*128, 0, 2048, Asl, Bsl);
}

// Wo projection, split-K2: z in {0,1} computes K-half into fp32 partial -> 1024 blocks (4/CU)
__global__ __launch_bounds__(256) void gemm_wo_kernel(const u16* __restrict__ A,
                                                      const u16* __restrict__ WoT,
                                                      float* __restrict__ part){
  __shared__ u16 Asl[128*64];
  __shared__ u16 Bsl[128*64];
  const int z = blockIdx.z;
  gemm_tile<2>(A, WoT, nullptr, part + (size_t)z*8388608,
               blockIdx.y*128, blockIdx.x*128, z*1024, z*1024+1024, Asl, Bsl);
}

// out = p0 + p1 + bias (row-major [4096][2048] fp32)
__global__ __launch_bounds__(256) void add_bias_kernel(const float* __restrict__ p0,
                                                       const float* __restrict__ p1,
                                                       const float* __restrict__ bias,
                                                       float* __restrict__ out){
  size_t i = ((size_t)blockIdx.x * 256 + threadIdx.x) * 4;
  float4 a = *(const float4*)(p0 + i);
  float4 b = *(const float4*)(p1 + i);
  float4 c = *(const float4*)(bias + (i & 2047));
  float4 o; o.x = a.x+b.x+c.x; o.y = a.y+b.y+c.y; o.z = a.z+b.z+c.z; o.w = a.w+b.w+c.w;
  *(float4*)(out + i) = o;
}

// ---------------- RoPE in place on bf16 [B,S,H,D], one wave per (b,s,h) row ----------------
__global__ __launch_bounds__(256) void rope_kernel(u16* __restrict__ Q, u16* __restrict__ Kb){
  const int wrow = blockIdx.x*4 + (threadIdx.x >> 6);  // 0 .. 65535 over (b,s,h)
  const int lane = threadIdx.x & 63;
  u16* P = (blockIdx.y == 0) ? Q : Kb;
  const int s = (wrow >> 4) & 2047;
  const size_t base = (size_t)wrow * 128;
  float invf = exp2f(-(float)lane * 0.20762050593045952f);  // log2(10000)/64
  float angle = (float)s * invf;
  float sn, cs;
  sincosf(angle, &sn, &cs);
  float x_j   = bf2f(P[base + lane]);
  float x_j64 = bf2f(P[base + 64 + lane]);
  float x_2j  = bf2f(P[base + 2*lane]);
  float x_2j1 = bf2f(P[base + 2*lane + 1]);
  float o0 = x_j  * cs - x_2j1 * sn;
  float o1 = x_j64 * cs + x_2j  * sn;
  P[base + lane]      = f2bf(o0);
  P[base + 64 + lane] = f2bf(o1);
}

// ---------------- transpose V: [B,S,H,D] -> VT [B,H,D,S] ----------------
__global__ __launch_bounds__(256) void transpose_v_kernel(const u16* __restrict__ V, u16* __restrict__ VT){
  __shared__ u16 t[64*72];
  const int s0 = blockIdx.x*64;
  const int d0 = blockIdx.y*64;
  const int bh = blockIdx.z;
  const int b = bh >> 4, h = bh & 15;
  const size_t obase = ((size_t)bh*128 + d0)*2048 + s0;
  const int tid = threadIdx.x;
  #pragma unroll
  for (int i=0;i<2;i++){
    int c = tid + i*256;
    int sl = c >> 3, dc = (c & 7) * 8;
    *(uint4*)(t + sl*72 + dc) =
      *(const uint4*)(V + ((size_t)(b*2048 + s0 + sl))*2048 + h*128 + d0 + dc);
  }
  __syncthreads();
  #pragma unroll
  for (int i=0;i<2;i++){
    int c = tid + i*256;
    int dl = c >> 3, sc4 = (c & 7) * 8;
    u16 tmp[8];
    #pragma unroll
    for (int j=0;j<8;j++) tmp[j] = t[(sc4+j)*72 + dl];
    *(uint4*)(VT + obase + (size_t)dl*2048 + sc4) = *(const uint4*)tmp;
  }
}

// ---------------- flash attention v6: 8-wave key-split (VGPR-cap fixed) ----------------
// 512 threads = 8 waves. Waves w&3 own q-rows [q0 + (w&3)*32, +32); group grp=w>>2 handles
// key-half [grp*32, grp*32+32) of every 64-key tile. Shared dbuf K/V tiles, 64KB LDS ->
// 2 blocks/CU -> 16 waves/CU = 4 waves/SIMD. v5's __launch_bounds__(512,4) capped VGPR at 64
// and spilled accO to scratch (FETCH 139->800MB, 247us). (512,2) -> cap 128, natural ~120,
// no spill, same residency target.
__global__ __launch_bounds__(512,2) void attn_kernel(const u16* __restrict__ Q,
                                                     const u16* __restrict__ K,
                                                     const u16* __restrict__ VT,
                                                     const int* __restrict__ mask,
                                                     u16* __restrict__ Out){
  constexpr int S = 2048;
  constexpr float SL2 = 0.08838834764831845f * 1.4426950408889634f;  // 1/sqrt(128) * log2(e)
  __shared__ u16 smem[32768];          // 64 KB: two 32KB buffers {K [64][128], V [128][64]}

  const int tid = threadIdx.x, w = tid >> 6, lane = tid & 63;
  const int wg  = w & 3;               // q-row group
  const int grp = w >> 2;              // key-half group
  const int qc = lane & 31;            // owned q-row; also key-row / d-row for A-frag reads
  const int h  = lane >> 5;            // k-slice half (A/B frag: k = 8*h + j)
  const int l7 = lane & 7;
  const int hh = blockIdx.y, b = blockIdx.z;
  const int q0 = blockIdx.x * 128;
  const size_t rowb = (size_t)b * 2048;
  const size_t bhD  = ((size_t)(b*16 + hh)) * 128;

  // Q fragments (B-operand: col = q = qc, k = d = 16t + 8h + j) straight from global (read once)
  s8v qf[8];
  {
    const u16* qp = Q + (rowb + q0 + wg*32 + qc)*2048 + hh*128 + h*8;
    #pragma unroll
    for (int t=0;t<8;t++){ Frag f; f.u = *(const uint4*)(qp + t*16); qf[t] = f.s; }
  }

  f32x16 accO[4];                      // O^T: [d-block][16 regs]; row=d local, col=q=qc
  #pragma unroll
  for (int d=0; d<4; d++) accO[d] = (f32x16)0.f;
  float lsum = 0.f;

  const int sr4 = lane >> 4, sp16 = lane & 15;   // K staging: 4 rows x 16 blocks per instr
  const int vr8 = lane >> 3, vp8 = lane & 7;     // V staging: 8 rows x 8 blocks per instr

  // stage K tile [64][128] + V tile [128][64]; 8 waves, 2+2 instrs each
  auto stage = [&](u16* base, int key0){
    u16* Kd = base;
    u16* Vd = base + 8192;
    #pragma unroll
    for (int i=0;i<2;i++){
      int R = w*8 + i*4;                          // K rows [w*8, w*8+8)
      int ob = sp16 ^ ((R&7) + sr4);              // (R+sr4)&7: R&7 in {0,4}, sr4<4
      async16(K + (rowb + key0 + R + sr4)*2048 + hh*128 + ob*8, Kd + R*128);
    }
    #pragma unroll
    for (int i=0;i<2;i++){
      int R = w*16 + i*8;                         // V d-rows [w*16, w*16+16)
      int ob = vp8 ^ vr8;                         // (R&7)==0
      async16(VT + (bhD + R + vr8)*2048 + key0 + ob*8, Vd + R*64);
    }
  };

  // ---- prologue: stage tile 0, mask row 0 ----
  stage(smem, 0);
  int mv = mask[b*S + lane];
  __syncthreads();                                 // drains vmcnt -> buf0 ready
  unsigned long long bm = __ballot(mv != 0);
  int cur = 0;

  for (int it=0; it<32; ++it){
    // ---- issue next tile's loads before compute (2-phase pipeline) ----
    if (it < 31){
      stage(smem + (cur^1)*16384, (it+1)*64);
      mv = mask[b*S + (it+1)*64 + lane];
    }
    const u16* Ks = smem + cur*16384;              // [64 keys][128 d]
    const u16* Vs = Ks + 8192;                     // [128 d][64 keys]

    // ---- S^T[key=grp*32+..][q] = K Q^T (this group's 32 keys) ----
    f32x16 sc = (f32x16)0.f;
    __builtin_amdgcn_s_setprio(1);
    #pragma unroll
    for (int t=0;t<8;t++){
      Frag kf; kf.u = *(const uint4*)(Ks + (grp*32 + qc)*128 + (((2*t + h) ^ l7)*8));
      sc = __builtin_amdgcn_mfma_f32_32x32x16_bf16(kf.s, qf[t], sc, 0, 0, 0);
    }
    __builtin_amdgcn_s_setprio(0);
    // ---- P = exp(score/sqrt(d)) (no-max softmax), lane-local row sum ----
    float p[16];
    #pragma unroll
    for (int m=0; m<16; ++m) p[m] = exp2f(sc[m] * SL2);
    if (bm != ~0ull){                              // wave-uniform fast path: mask all valid
      #pragma unroll
      for (int m=0; m<16; ++m){
        int bit = grp*32 + (m&3) + 8*(m>>2) + 4*h;
        if (!((bm >> bit) & 1ull)) p[m] = 0.f;
      }
    }
    #pragma unroll
    for (int m=0; m<16; ++m) lsum += p[m];

    // ---- build P^T B-frags in-register and do PV ----
    #pragma unroll
    for (int gi=0; gi<2; ++gi){                    // 16-key sub-tile -> one frag
      u32 a0 = cvtpk(p[8*gi+0], p[8*gi+1]);        // keys 4h+{0,1}   (+16gi local)
      u32 a1 = cvtpk(p[8*gi+2], p[8*gi+3]);        // keys 4h+{2,3}
      u32 a2 = cvtpk(p[8*gi+4], p[8*gi+5]);        // keys 8+4h+{0,1}
      u32 a3 = cvtpk(p[8*gi+6], p[8*gi+7]);        // keys 8+4h+{2,3}
      u32x2 r0 = __builtin_amdgcn_permlane32_swap(a0, a2, false, false);
      u32x2 r1 = __builtin_amdgcn_permlane32_swap(a1, a3, false, false);
      // frag elems j=0..7 = P[qc][16T + 8h + j]  (T indexes the tile's four 16-key slices)
      Frag pf; pf.u = make_uint4(r0[0], r1[0], r0[1], r1[1]);
      const int T = grp*2 + gi;
      __builtin_amdgcn_s_setprio(1);
      #pragma unroll
      for (int d=0; d<4; ++d){
        Frag vf; vf.u = *(const uint4*)(Vs + (d*32 + qc)*64 + (((2*T + h) ^ l7)*8));
        accO[d] = __builtin_amdgcn_mfma_f32_32x32x16_bf16(vf.s, pf.s, accO[d], 0, 0, 0);
      }
      __builtin_amdgcn_s_setprio(0);
    }
    __syncthreads();                               // all waves done with buf[cur]; buf[cur^1] staged
    bm = __ballot(mv != 0);
    cur ^= 1;
  }

  // ---- merge the two key-half groups: l and O are pure sums (no-max softmax) ----
  float sg = lsum + __shfl_xor(lsum, 32, 64);      // this group's row sum (both h halves)
  float* red = (float*)smem;
  __syncthreads();                                 // done with K/V buffers
  if (grp == 1) red[wg*64 + lane] = sg;
  __syncthreads();
  float invv = 0.f;
  if (grp == 0){
    float tot = sg + red[wg*64 + lane];
    invv = (tot > 0.f) ? 1.f/tot : 0.f;
  }
  __syncthreads();
  if (grp == 1){                                   // ship accO: [elem][lane] layout, conflict-free
    float* dst = red + wg*4096;
    #pragma unroll
    for (int d=0; d<4; ++d)
      #pragma unroll
      for (int j=0; j<16; ++j) dst[(d*16+j)*64 + lane] = accO[d][j];
  }
  __syncthreads();
  if (grp == 0){
    const float* src = red + wg*4096;
    #pragma unroll
    for (int d=0; d<4; ++d)
      #pragma unroll
      for (int j=0; j<16; ++j) accO[d][j] += src[(d*16+j)*64 + lane];

    u16* orow = Out + (rowb + q0 + wg*32 + qc)*2048 + hh*128;
    #pragma unroll
    for (int d=0; d<4; ++d){
      #pragma unroll
      for (int g2=0; g2<4; ++g2){
        uint2 o;
        o.x = cvtpk(accO[d][g2*4+0] * invv, accO[d][g2*4+1] * invv);
        o.y = cvtpk(accO[d][g2*4+2] * invv, accO[d][g2*4+3] * invv);
        *(uint2*)(orow + d*32 + g2*8 + 4*h) = o;   // d_local = (reg&3)+8*(reg>>2)+4h
      }
    }
  }
}

extern "C" void kernel_launch(void* const* d_in, const int* in_sizes, int n_in,
                              void* d_out, int out_size, void* d_ws, size_t ws_size,
                              hipStream_t stream) {
  (void)in_sizes; (void)n_in; (void)out_size; (void)ws_size;
  const float* x    = (const float*)d_in[0];
  const int*   mask = (const int*)d_in[1];
  const float* Wq   = (const float*)d_in[2];
  const float* bq   = (const float*)d_in[3];
  const float* Wk   = (const float*)d_in[4];
  const float* bk   = (const float*)d_in[5];
  const float* Wv   = (const float*)d_in[6];
  const float* bv   = (const float*)d_in[7];
  const float* Wo   = (const float*)d_in[8];
  const float* bo   = (const float*)d_in[9];

  u16* xbf = (u16*)d_ws;                 // 8388608 elems
  u16* WqT = xbf + 8388608;              // 4194304 each
  u16* WkT = WqT + 4194304;
  u16* WvT = WkT + 4194304;
  u16* WoT = WvT + 4194304;
  u16* Qb  = WoT + 4194304;              // 8388608 each, [B,S,H,D] row-major
  u16* Kb  = Qb + 8388608;
  u16* Vb  = Kb + 8388608;
  u16* VTb = Vb + 8388608;               // V transposed [B,H,D,S]
  u16* Ab  = VTb + 8388608;              // attn out bf16 [B,S,E]
  // after attn, Qb/Kb/Vb/VTb are dead -> reuse as fp32 split-K partials for the Wo GEMM
  float* part = (float*)Qb;              // part0 = Qb..Kb (8388608 f32), part1 = Vb..VTb

  cast_x_kernel<<<8192, 256, 0, stream>>>(x, xbf);
  cast_transpose_kernel<<<dim3(32,32,4), 256, 0, stream>>>(Wq, Wk, Wv, Wo, WqT, WkT, WvT, WoT);
  gemm_qkv_kernel<<<dim3(48,32), 256, 0, stream>>>(xbf, WqT, WkT, WvT, bq, bk, bv, Qb, Kb, Vb);
  rope_kernel<<<dim3(16384,2), 256, 0, stream>>>(Qb, Kb);
  transpose_v_kernel<<<dim3(32,2,32), 256, 0, stream>>>(Vb, VTb);
  attn_kernel<<<dim3(16,16,2), 512, 0, stream>>>(Qb, Kb, VTb, mask, Ab);
  gemm_wo_kernel<<<dim3(16,32,2), 256, 0, stream>>>(Ab, WoT, part);
  add_bias_kernel<<<8192, 256, 0, stream>>>(part, part + 8388608, bo, (float*)d_out);
}

// Round 7
// 419.608 us; speedup vs baseline: 1.4212x; 1.1416x over previous
//
#include <hip/hip_runtime.h>
#include <hip/hip_bf16.h>
#include <cmath>

typedef unsigned short u16;
typedef unsigned int   u32;

using v4f    = __attribute__((ext_vector_type(4)))  float;
using f32x16 = __attribute__((ext_vector_type(16))) float;
using s8v    = __attribute__((ext_vector_type(8)))  short;
using u32x2  = __attribute__((ext_vector_type(2)))  unsigned int;

union Frag { uint4 u; s8v s; };

__device__ __forceinline__ u16 f2bf(float f){
  u32 u = __float_as_uint(f);
  u32 r = u + 0x7fffu + ((u >> 16) & 1u);
  return (u16)(r >> 16);
}
__device__ __forceinline__ float bf2f(u16 h){ return __uint_as_float(((u32)h) << 16); }

// pack two f32 -> one dword of 2 bf16 (RNE), single VALU op (T12 recipe; no builtin on gfx950)
__device__ __forceinline__ u32 cvtpk(float a, float b){
  u32 r;
  asm("v_cvt_pk_bf16_f32 %0, %1, %2" : "=v"(r) : "v"(a), "v"(b));
  return r;
}

// async global->LDS, 16B per lane; LDS dest is wave-uniform base + lane*16
__device__ __forceinline__ void async16(const void* g, void* l){
  __builtin_amdgcn_global_load_lds((__attribute__((address_space(1))) void*)g,
                                   (__attribute__((address_space(3))) void*)l, 16, 0, 0);
}

// ---------------- fused prep: cast x (fp32->bf16) + cast/transpose 4 weight matrices ----------------
// blocks [0,8192): cast_x ; blocks [8192,12288): cast_transpose. Branch is block-uniform.
__global__ __launch_bounds__(256) void prep_kernel(
    const float* __restrict__ x, u16* __restrict__ xb,
    const float* __restrict__ W0, const float* __restrict__ W1,
    const float* __restrict__ W2, const float* __restrict__ W3,
    u16* __restrict__ T0, u16* __restrict__ T1, u16* __restrict__ T2, u16* __restrict__ T3){
  __shared__ float tile[64][65];
  const int bid = blockIdx.x;
  if (bid < 8192){
    size_t i = ((size_t)bid * 256 + threadIdx.x) * 4;
    float4 v = *(const float4*)(x + i);
    uint2 o;
    o.x = (u32)f2bf(v.x) | ((u32)f2bf(v.y) << 16);
    o.y = (u32)f2bf(v.z) | ((u32)f2bf(v.w) << 16);
    *(uint2*)(xb + i) = o;
    return;
  }
  const int t4 = bid - 8192;          // [0,4096): z=t4>>10, y=(t4&1023)>>5, x=t4&31
  const int z  = t4 >> 10;
  const float* W = (z==0)?W0:(z==1)?W1:(z==2)?W2:W3;
  u16*         T = (z==0)?T0:(z==1)?T1:(z==2)?T2:T3;
  const int k0 = ((t4 & 1023) >> 5)*64, n0 = (t4 & 31)*64;
  const int t  = threadIdx.x;
  const int rr = t >> 4, c4 = (t & 15) * 4;
  #pragma unroll
  for (int i=0;i<4;i++){
    int k = rr + i*16;
    float4 v = *(const float4*)(W + (size_t)(k0+k)*2048 + n0 + c4);
    tile[k][c4+0]=v.x; tile[k][c4+1]=v.y; tile[k][c4+2]=v.z; tile[k][c4+3]=v.w;
  }
  __syncthreads();
  #pragma unroll
  for (int i=0;i<4;i++){
    int n = rr + i*16;
    uint2 o;
    o.x = (u32)f2bf(tile[c4+0][n]) | ((u32)f2bf(tile[c4+1][n])<<16);
    o.y = (u32)f2bf(tile[c4+2][n]) | ((u32)f2bf(tile[c4+3][n])<<16);
    *(uint2*)(T + (size_t)(n0+n)*2048 + k0 + c4) = o;
  }
}

// ---------------- bf16 MFMA GEMM core (m97-style) ----------------
// C[128x128 tile] = A * BT^T + bias. LDS tiles 128x64 u16, unpadded, 16B-block XOR swizzle.
// MODE 0: bf16 out. MODE 1: fp32 out.
template<int MODE>
__device__ __forceinline__ void gemm_tile(const u16* __restrict__ A, const u16* __restrict__ BT,
                                          const float* __restrict__ bias, void* __restrict__ Cout,
                                          int m0, int n0, u16* Asl, u16* Bsl){
  constexpr int K = 2048;
  const int tid  = threadIdx.x;
  const int w    = tid >> 6;
  const int lane = tid & 63;
  const int r    = lane & 15, q = lane >> 4;
  const int wm   = (w >> 1) * 64, wn = (w & 1) * 64;

  v4f acc[4][4];
  #pragma unroll
  for (int i=0;i<4;i++)
    #pragma unroll
    for (int j=0;j<4;j++) acc[i][j] = (v4f)0.f;

  // staging geometry: per instr 8 rows x 8 blocks; wave w covers rows [w*32, w*32+32)
  const int srow = w*32 + (lane>>3);
  const int sblk = (lane&7) ^ ((lane>>3)&7);   // swizzled source block for this lane's LDS slot
  const u16* Ag = A  + (size_t)(m0+srow)*K + sblk*8;
  const u16* Bg = BT + (size_t)(n0+srow)*K + sblk*8;
  u16* Als = Asl + (w*32)*64;
  u16* Bls = Bsl + (w*32)*64;

  for (int kk = 0; kk < K; kk += 64) {
    #pragma unroll
    for (int i=0;i<4;i++){
      async16(Ag + (size_t)i*8*K + kk, Als + i*512);
      async16(Bg + (size_t)i*8*K + kk, Bls + i*512);
    }
    __syncthreads();
    #pragma unroll
    for (int ks=0; ks<2; ++ks) {
      s8v af[4], bfr[4];
      #pragma unroll
      for (int i=0;i<4;i++){
        int rho = wm + i*16 + r;
        int p = (ks*4 + q) ^ (r&7);
        Frag t; t.u = *(const uint4*)(Asl + rho*64 + p*8); af[i] = t.s;
      }
      #pragma unroll
      for (int j=0;j<4;j++){
        int rho = wn + j*16 + r;
        int p = (ks*4 + q) ^ (r&7);
        Frag t; t.u = *(const uint4*)(Bsl + rho*64 + p*8); bfr[j] = t.s;
      }
      #pragma unroll
      for (int i=0;i<4;i++)
        #pragma unroll
        for (int j=0;j<4;j++)
          acc[i][j] = __builtin_amdgcn_mfma_f32_16x16x32_bf16(af[i], bfr[j], acc[i][j], 0, 0, 0);
    }
    __syncthreads();
  }

  float bv[4];
  #pragma unroll
  for (int j=0;j<4;j++) bv[j] = bias[n0 + wn + j*16 + r];

  #pragma unroll
  for (int i=0;i<4;i++){
    #pragma unroll
    for (int j=0;j<4;j++){
      const int gn = n0 + wn + j*16 + r;
      #pragma unroll
      for (int rr2=0; rr2<4; ++rr2){
        const int gm = m0 + wm + i*16 + q*4 + rr2;
        float val = acc[i][j][rr2] + bv[j];
        if (MODE == 0) ((u16*)Cout)[(size_t)gm*2048 + gn] = f2bf(val);
        else           ((float*)Cout)[(size_t)gm*2048 + gn] = val;
      }
    }
  }
}

// fused Q/K/V projection, 1536 blocks, XCD-aware bijective swizzle (1536%8==0).
__global__ __launch_bounds__(256) void gemm_qkv_kernel(
    const u16* __restrict__ A,
    const u16* __restrict__ WqT, const u16* __restrict__ WkT, const u16* __restrict__ WvT,
    const float* __restrict__ bq, const float* __restrict__ bk, const float* __restrict__ bv,
    u16* __restrict__ Qb, u16* __restrict__ Kb, u16* __restrict__ Vb){
  __shared__ u16 Asl[128*64];
  __shared__ u16 Bsl[128*64];
  const int L   = blockIdx.x + 48*blockIdx.y;      // original linear id (x fastest)
  const int wid = (L & 7)*192 + (L >> 3);          // XCD chunk: each XCD -> contiguous work ids
  const int bx  = wid % 48, by = wid / 48;
  const int mat = bx >> 4;                         // 0:Q 1:K 2:V
  const u16*   BT   = (mat==0)?WqT:(mat==1)?WkT:WvT;
  const float* bias = (mat==0)?bq :(mat==1)?bk :bv;
  u16*         Cout = (mat==0)?Qb :(mat==1)?Kb :Vb;
  gemm_tile<0>(A, BT, bias, Cout, by*128, (bx & 15)*128, Asl, Bsl);
}

// Wo projection (fp32 out + bias), 512 blocks, XCD swizzle (512%8==0).
__global__ __launch_bounds__(256) void gemm_wo_kernel(const u16* __restrict__ A,
                                                      const u16* __restrict__ WoT,
                                                      const float* __restrict__ bias,
                                                      float* __restrict__ out){
  __shared__ u16 Asl[128*64];
  __shared__ u16 Bsl[128*64];
  const int L   = blockIdx.x + 16*blockIdx.y;
  const int wid = (L & 7)*64 + (L >> 3);
  const int bx  = wid % 16, by = wid / 16;
  gemm_tile<1>(A, WoT, bias, out, by*128, bx*128, Asl, Bsl);
}

// ---------------- fused rope (in-place Q,K) + transpose V -> VT ----------------
// blocks [0,32768): rope ; blocks [32768,34816): transpose_v. Block-uniform branch.
__global__ __launch_bounds__(256) void rope_tv_kernel(u16* __restrict__ Q, u16* __restrict__ Kb,
                                                      const u16* __restrict__ V, u16* __restrict__ VT){
  __shared__ u16 t[64*72];
  const int bid = blockIdx.x;
  if (bid < 32768){
    const int ry = bid >> 14;                       // 0:Q 1:K
    const int rx = bid & 16383;
    const int wrow = rx*4 + (threadIdx.x >> 6);     // 0 .. 65535 over (b,s,h)
    const int lane = threadIdx.x & 63;
    u16* P = (ry == 0) ? Q : Kb;
    const int s = (wrow >> 4) & 2047;
    const size_t base = (size_t)wrow * 128;
    float invf = exp2f(-(float)lane * 0.20762050593045952f);  // log2(10000)/64
    float angle = (float)s * invf;
    float sn, cs;
    sincosf(angle, &sn, &cs);
    float x_j   = bf2f(P[base + lane]);
    float x_j64 = bf2f(P[base + 64 + lane]);
    float x_2j  = bf2f(P[base + 2*lane]);
    float x_2j1 = bf2f(P[base + 2*lane + 1]);
    float o0 = x_j  * cs - x_2j1 * sn;
    float o1 = x_j64 * cs + x_2j  * sn;
    P[base + lane]      = f2bf(o0);
    P[base + 64 + lane] = f2bf(o1);
    return;
  }
  const int tb = bid - 32768;                       // [0,2048): x=tb&31, y=(tb>>5)&1, z=tb>>6
  const int s0 = (tb & 31)*64;
  const int d0 = ((tb >> 5) & 1)*64;
  const int bh = tb >> 6;
  const int b = bh >> 4, h = bh & 15;
  const size_t obase = ((size_t)bh*128 + d0)*2048 + s0;
  const int tid = threadIdx.x;
  #pragma unroll
  for (int i=0;i<2;i++){
    int c = tid + i*256;
    int sl = c >> 3, dc = (c & 7) * 8;
    *(uint4*)(t + sl*72 + dc) =
      *(const uint4*)(V + ((size_t)(b*2048 + s0 + sl))*2048 + h*128 + d0 + dc);
  }
  __syncthreads();
  #pragma unroll
  for (int i=0;i<2;i++){
    int c = tid + i*256;
    int dl = c >> 3, sc4 = (c & 7) * 8;
    u16 tmp[8];
    #pragma unroll
    for (int j=0;j<8;j++) tmp[j] = t[(sc4+j)*72 + dl];
    *(uint4*)(VT + obase + (size_t)dl*2048 + sc4) = *(const uint4*)tmp;
  }
}

// ---------------- flash attention (r4-best): 4 waves, double-buffered K/V, in-reg softmax ----------------
// 32x32x16 MFMA. Q-tile 128 (4 waves x 32 q-rows), K-tile 64. LDS 64KB: 2 x {K [64][128] + V [128][64]},
// unpadded with 16B-block XOR swizzle (pos = blk ^ (row&7)).
// Swapped QK^T: S^T = mfma(A=K, B=Q); P^T frags via v_cvt_pk_bf16_f32 + permlane32_swap;
// O^T = mfma(A=V^T, B=P^T) -> lane-local 1/l normalization. Measured 104.6us (r4).
__global__ __launch_bounds__(256,2) void attn_kernel(const u16* __restrict__ Q,
                                                     const u16* __restrict__ K,
                                                     const u16* __restrict__ VT,
                                                     const int* __restrict__ mask,
                                                     u16* __restrict__ Out){
  constexpr int S = 2048;
  constexpr float SL2 = 0.08838834764831845f * 1.4426950408889634f;  // 1/sqrt(128) * log2(e)
  __shared__ u16 smem[32768];          // 64 KB: two 32KB buffers

  const int tid = threadIdx.x, w = tid >> 6, lane = tid & 63;
  const int qc = lane & 31;            // owned q-row; also key-row / d-row for A-frag reads
  const int h  = lane >> 5;            // k-slice half (A/B frag: k = 8*h + j)
  const int l7 = lane & 7;
  const int hh = blockIdx.y, b = blockIdx.z;
  const int q0 = blockIdx.x * 128;
  const size_t rowb = (size_t)b * 2048;
  const size_t bhD  = ((size_t)(b*16 + hh)) * 128;

  // Q fragments (B-operand: col = q = qc, k = d = 16t + 8h + j) straight from global (read once)
  s8v qf[8];
  {
    const u16* qp = Q + (rowb + q0 + w*32 + qc)*2048 + hh*128 + h*8;
    #pragma unroll
    for (int t=0;t<8;t++){ Frag f; f.u = *(const uint4*)(qp + t*16); qf[t] = f.s; }
  }

  f32x16 accO[4];                      // O^T: [d-block][16 regs]; row=d local, col=q=qc
  #pragma unroll
  for (int d=0; d<4; d++) accO[d] = (f32x16)0.f;
  float lsum = 0.f;

  const int sr4 = lane >> 4, sp16 = lane & 15;   // K staging: 4 rows x 16 blocks per instr
  const int vr8 = lane >> 3, vp8 = lane & 7;     // V staging: 8 rows x 8 blocks per instr

  // stage K tile [64][128] + V tile [128][64] for key block at key0 into buffer `base`
  auto stage = [&](u16* base, int key0){
    u16* Kd = base;
    u16* Vd = base + 8192;
    #pragma unroll
    for (int i=0;i<4;i++){
      int R = w*16 + i*4;
      int ob = sp16 ^ ((R&7) + sr4);              // (R+sr4)&7: R&7 in {0,4}, sr4<4
      async16(K + (rowb + key0 + R + sr4)*2048 + hh*128 + ob*8, Kd + R*128);
    }
    #pragma unroll
    for (int i=0;i<4;i++){
      int R = w*32 + i*8;
      int ob = vp8 ^ vr8;                         // (R&7)==0
      async16(VT + (bhD + R + vr8)*2048 + key0 + ob*8, Vd + R*64);
    }
  };

  // ---- prologue: stage tile 0, mask row 0 ----
  stage(smem, 0);
  int mv = mask[b*S + lane];
  __syncthreads();                                 // drains vmcnt -> buf0 ready
  unsigned long long bm = __ballot(mv != 0);
  int cur = 0;

  for (int it=0; it<32; ++it){
    // ---- issue next tile's loads before compute (2-phase pipeline) ----
    if (it < 31){
      stage(smem + (cur^1)*16384, (it+1)*64);
      mv = mask[b*S + (it+1)*64 + lane];
    }
    const u16* Ks = smem + cur*16384;              // [64 keys][128 d]
    const u16* Vs = Ks + 8192;                     // [128 d][64 keys]

    #pragma unroll
    for (int nb=0; nb<2; ++nb){
      // ---- S^T[key=nb*32+..][q] = K Q^T ----
      f32x16 sc = (f32x16)0.f;
      __builtin_amdgcn_s_setprio(1);
      #pragma unroll
      for (int t=0;t<8;t++){
        Frag kf; kf.u = *(const uint4*)(Ks + (nb*32 + qc)*128 + (((2*t + h) ^ l7)*8));
        sc = __builtin_amdgcn_mfma_f32_32x32x16_bf16(kf.s, qf[t], sc, 0, 0, 0);
      }
      __builtin_amdgcn_s_setprio(0);
      // ---- P = exp(score/sqrt(d)) (no-max softmax), lane-local row sum ----
      float p[16];
      #pragma unroll
      for (int m=0; m<16; ++m) p[m] = exp2f(sc[m] * SL2);
      if (bm != ~0ull){                            // wave-uniform fast path: mask all valid
        #pragma unroll
        for (int m=0; m<16; ++m){
          int bit = nb*32 + (m&3) + 8*(m>>2) + 4*h;
          if (!((bm >> bit) & 1ull)) p[m] = 0.f;
        }
      }
      #pragma unroll
      for (int m=0; m<16; ++m) lsum += p[m];

      // ---- build P^T B-frags in-register and do PV ----
      #pragma unroll
      for (int g=0; g<2; ++g){                     // 16-key sub-tile -> one frag
        u32 a0 = cvtpk(p[8*g+0], p[8*g+1]);        // keys 4h+{0,1}   (+16g local)
        u32 a1 = cvtpk(p[8*g+2], p[8*g+3]);        // keys 4h+{2,3}
        u32 a2 = cvtpk(p[8*g+4], p[8*g+5]);        // keys 8+4h+{0,1}
        u32 a3 = cvtpk(p[8*g+6], p[8*g+7]);        // keys 8+4h+{2,3}
        u32x2 r0 = __builtin_amdgcn_permlane32_swap(a0, a2, false, false);
        u32x2 r1 = __builtin_amdgcn_permlane32_swap(a1, a3, false, false);
        // frag elems j=0..7 = P[qc][16T + 8h + j]
        Frag pf; pf.u = make_uint4(r0[0], r1[0], r0[1], r1[1]);
        const int T = nb*2 + g;
        __builtin_amdgcn_s_setprio(1);
        #pragma unroll
        for (int d=0; d<4; ++d){
          Frag vf; vf.u = *(const uint4*)(Vs + (d*32 + qc)*64 + (((2*T + h) ^ l7)*8));
          accO[d] = __builtin_amdgcn_mfma_f32_32x32x16_bf16(vf.s, pf.s, accO[d], 0, 0, 0);
        }
        __builtin_amdgcn_s_setprio(0);
      }
    }
    __syncthreads();                               // all waves done with buf[cur]; buf[cur^1] staged
    bm = __ballot(mv != 0);
    cur ^= 1;
  }

  // ---- row sum across the two k-slice halves, normalize, store ----
  float sall = lsum + __shfl_xor(lsum, 32, 64);
  float invv = (sall > 0.f) ? 1.f/sall : 0.f;
  u16* orow = Out + (rowb + q0 + w*32 + qc)*2048 + hh*128;
  #pragma unroll
  for (int d=0; d<4; ++d){
    #pragma unroll
    for (int g2=0; g2<4; ++g2){
      uint2 o;
      o.x = cvtpk(accO[d][g2*4+0] * invv, accO[d][g2*4+1] * invv);
      o.y = cvtpk(accO[d][g2*4+2] * invv, accO[d][g2*4+3] * invv);
      *(uint2*)(orow + d*32 + g2*8 + 4*h) = o;     // d_local = (reg&3)+8*(reg>>2)+4h
    }
  }
}

extern "C" void kernel_launch(void* const* d_in, const int* in_sizes, int n_in,
                              void* d_out, int out_size, void* d_ws, size_t ws_size,
                              hipStream_t stream) {
  (void)in_sizes; (void)n_in; (void)out_size; (void)ws_size;
  const float* x    = (const float*)d_in[0];
  const int*   mask = (const int*)d_in[1];
  const float* Wq   = (const float*)d_in[2];
  const float* bq   = (const float*)d_in[3];
  const float* Wk   = (const float*)d_in[4];
  const float* bk   = (const float*)d_in[5];
  const float* Wv   = (const float*)d_in[6];
  const float* bv   = (const float*)d_in[7];
  const float* Wo   = (const float*)d_in[8];
  const float* bo   = (const float*)d_in[9];

  u16* xbf = (u16*)d_ws;                 // 8388608 elems
  u16* WqT = xbf + 8388608;              // 4194304 each
  u16* WkT = WqT + 4194304;
  u16* WvT = WkT + 4194304;
  u16* WoT = WvT + 4194304;
  u16* Qb  = WoT + 4194304;              // 8388608 each, [B,S,H,D] row-major
  u16* Kb  = Qb + 8388608;
  u16* Vb  = Kb + 8388608;
  u16* VTb = Vb + 8388608;               // V transposed [B,H,D,S]
  u16* Ab  = VTb + 8388608;              // attn out bf16 [B,S,E]

  prep_kernel<<<12288, 256, 0, stream>>>(x, xbf, Wq, Wk, Wv, Wo, WqT, WkT, WvT, WoT);
  gemm_qkv_kernel<<<dim3(48,32), 256, 0, stream>>>(xbf, WqT, WkT, WvT, bq, bk, bv, Qb, Kb, Vb);
  rope_tv_kernel<<<34816, 256, 0, stream>>>(Qb, Kb, Vb, VTb);
  attn_kernel<<<dim3(16,16,2), 256, 0, stream>>>(Qb, Kb, VTb, mask, Ab);
  gemm_wo_kernel<<<dim3(16,32), 256, 0, stream>>>(Ab, WoT, bo, (float*)d_out);
}

// Round 8
// 404.310 us; speedup vs baseline: 1.4749x; 1.0378x over previous
//
#include <hip/hip_runtime.h>
#include <hip/hip_bf16.h>
#include <cmath>

typedef unsigned short u16;
typedef unsigned int   u32;

using v4f    = __attribute__((ext_vector_type(4)))  float;
using f32x16 = __attribute__((ext_vector_type(16))) float;
using s8v    = __attribute__((ext_vector_type(8)))  short;
using u32x2  = __attribute__((ext_vector_type(2)))  unsigned int;

union Frag { uint4 u; s8v s; };

__device__ __forceinline__ u16 f2bf(float f){
  u32 u = __float_as_uint(f);
  u32 r = u + 0x7fffu + ((u >> 16) & 1u);
  return (u16)(r >> 16);
}
__device__ __forceinline__ float bf2f(u16 h){ return __uint_as_float(((u32)h) << 16); }

// pack two f32 -> one dword of 2 bf16 (RNE), single VALU op (T12 recipe; no builtin on gfx950)
__device__ __forceinline__ u32 cvtpk(float a, float b){
  u32 r;
  asm("v_cvt_pk_bf16_f32 %0, %1, %2" : "=v"(r) : "v"(a), "v"(b));
  return r;
}

// async global->LDS, 16B per lane; LDS dest is wave-uniform base + lane*16
__device__ __forceinline__ void async16(const void* g, void* l){
  __builtin_amdgcn_global_load_lds((__attribute__((address_space(1))) void*)g,
                                   (__attribute__((address_space(3))) void*)l, 16, 0, 0);
}

// ---------------- fused prep: cast x (fp32->bf16) + cast/transpose 4 weight matrices ----------------
// blocks [0,8192): cast_x ; blocks [8192,12288): cast_transpose. Branch is block-uniform.
__global__ __launch_bounds__(256) void prep_kernel(
    const float* __restrict__ x, u16* __restrict__ xb,
    const float* __restrict__ W0, const float* __restrict__ W1,
    const float* __restrict__ W2, const float* __restrict__ W3,
    u16* __restrict__ T0, u16* __restrict__ T1, u16* __restrict__ T2, u16* __restrict__ T3){
  __shared__ float tile[64][65];
  const int bid = blockIdx.x;
  if (bid < 8192){
    size_t i = ((size_t)bid * 256 + threadIdx.x) * 4;
    float4 v = *(const float4*)(x + i);
    uint2 o;
    o.x = (u32)f2bf(v.x) | ((u32)f2bf(v.y) << 16);
    o.y = (u32)f2bf(v.z) | ((u32)f2bf(v.w) << 16);
    *(uint2*)(xb + i) = o;
    return;
  }
  const int t4 = bid - 8192;          // [0,4096): z=t4>>10, y=(t4&1023)>>5, x=t4&31
  const int z  = t4 >> 10;
  const float* W = (z==0)?W0:(z==1)?W1:(z==2)?W2:W3;
  u16*         T = (z==0)?T0:(z==1)?T1:(z==2)?T2:T3;
  const int k0 = ((t4 & 1023) >> 5)*64, n0 = (t4 & 31)*64;
  const int t  = threadIdx.x;
  const int rr = t >> 4, c4 = (t & 15) * 4;
  #pragma unroll
  for (int i=0;i<4;i++){
    int k = rr + i*16;
    float4 v = *(const float4*)(W + (size_t)(k0+k)*2048 + n0 + c4);
    tile[k][c4+0]=v.x; tile[k][c4+1]=v.y; tile[k][c4+2]=v.z; tile[k][c4+3]=v.w;
  }
  __syncthreads();
  #pragma unroll
  for (int i=0;i<4;i++){
    int n = rr + i*16;
    uint2 o;
    o.x = (u32)f2bf(tile[c4+0][n]) | ((u32)f2bf(tile[c4+1][n])<<16);
    o.y = (u32)f2bf(tile[c4+2][n]) | ((u32)f2bf(tile[c4+3][n])<<16);
    *(uint2*)(T + (size_t)(n0+n)*2048 + k0 + c4) = o;
  }
}

// ---------------- bf16 MFMA GEMM core (m97-style) ----------------
// C[128x128 tile] = A * BT^T + bias. LDS: one 32KB buffer sm; Asl=sm, Bsl=sm+8192 (128x64 u16
// tiles, unpadded, 16B-block XOR swizzle: data block b of row r stored at pos b^(r&7)).
// MODE 0: bf16 out. MODE 1: fp32 out. MODE 3: bf16 out + fused RoPE (n-tile == one head,
// all rotate_half partner columns are inside this block's C tile; stage tile in sm, then
// per-row sincos identical to the standalone rope pass -> numerically identical).
template<int MODE>
__device__ __forceinline__ void gemm_tile(const u16* __restrict__ A, const u16* __restrict__ BT,
                                          const float* __restrict__ bias, void* __restrict__ Cout,
                                          int m0, int n0, u16* sm){
  constexpr int K = 2048;
  u16* Asl = sm;
  u16* Bsl = sm + 8192;
  const int tid  = threadIdx.x;
  const int w    = tid >> 6;
  const int lane = tid & 63;
  const int r    = lane & 15, q = lane >> 4;
  const int wm   = (w >> 1) * 64, wn = (w & 1) * 64;

  v4f acc[4][4];
  #pragma unroll
  for (int i=0;i<4;i++)
    #pragma unroll
    for (int j=0;j<4;j++) acc[i][j] = (v4f)0.f;

  // staging geometry: per instr 8 rows x 8 blocks; wave w covers rows [w*32, w*32+32)
  const int srow = w*32 + (lane>>3);
  const int sblk = (lane&7) ^ ((lane>>3)&7);   // swizzled source block for this lane's LDS slot
  const u16* Ag = A  + (size_t)(m0+srow)*K + sblk*8;
  const u16* Bg = BT + (size_t)(n0+srow)*K + sblk*8;
  u16* Als = Asl + (w*32)*64;
  u16* Bls = Bsl + (w*32)*64;

  for (int kk = 0; kk < K; kk += 64) {
    #pragma unroll
    for (int i=0;i<4;i++){
      async16(Ag + (size_t)i*8*K + kk, Als + i*512);
      async16(Bg + (size_t)i*8*K + kk, Bls + i*512);
    }
    __syncthreads();
    #pragma unroll
    for (int ks=0; ks<2; ++ks) {
      s8v af[4], bfr[4];
      #pragma unroll
      for (int i=0;i<4;i++){
        int rho = wm + i*16 + r;
        int p = (ks*4 + q) ^ (r&7);
        Frag t; t.u = *(const uint4*)(Asl + rho*64 + p*8); af[i] = t.s;
      }
      #pragma unroll
      for (int j=0;j<4;j++){
        int rho = wn + j*16 + r;
        int p = (ks*4 + q) ^ (r&7);
        Frag t; t.u = *(const uint4*)(Bsl + rho*64 + p*8); bfr[j] = t.s;
      }
      #pragma unroll
      for (int i=0;i<4;i++)
        #pragma unroll
        for (int j=0;j<4;j++)
          acc[i][j] = __builtin_amdgcn_mfma_f32_16x16x32_bf16(af[i], bfr[j], acc[i][j], 0, 0, 0);
    }
    __syncthreads();
  }

  float bv[4];
  #pragma unroll
  for (int j=0;j<4;j++) bv[j] = bias[n0 + wn + j*16 + r];

  if constexpr (MODE != 3){
    #pragma unroll
    for (int i=0;i<4;i++){
      #pragma unroll
      for (int j=0;j<4;j++){
        const int gn = n0 + wn + j*16 + r;
        #pragma unroll
        for (int rr2=0; rr2<4; ++rr2){
          const int gm = m0 + wm + i*16 + q*4 + rr2;
          float val = acc[i][j][rr2] + bv[j];
          if (MODE == 0) ((u16*)Cout)[(size_t)gm*2048 + gn] = f2bf(val);
          else           ((float*)Cout)[(size_t)gm*2048 + gn] = val;
        }
      }
    }
  } else {
    // ---- stage bf16 C tile [128][128] in sm (Asl/Bsl dead after last barrier) ----
    #pragma unroll
    for (int i=0;i<4;i++)
      #pragma unroll
      for (int j=0;j<4;j++){
        const int col = wn + j*16 + r;
        #pragma unroll
        for (int rr2=0; rr2<4; ++rr2)
          sm[(wm + i*16 + q*4 + rr2)*128 + col] = f2bf(acc[i][j][rr2] + bv[j]);
      }
    __syncthreads();
    // ---- RoPE: wave w rows [w*32, w*32+32); lane = freq index j; 1 sincos/row/lane ----
    const float invf = exp2f(-(float)lane * 0.20762050593045952f);  // log2(10000)/64
    for (int rr=0; rr<32; ++rr){
      const int row = w*32 + rr;
      const int s = (m0 + row) & 2047;          // gm = b*2048+s, tiles never cross b
      float sn, cs;
      sincosf((float)s * invf, &sn, &cs);
      const u16* tr = sm + row*128;
      float x_j   = bf2f(tr[lane]);
      float x_j64 = bf2f(tr[64 + lane]);
      float x_2j  = bf2f(tr[2*lane]);
      float x_2j1 = bf2f(tr[2*lane + 1]);
      u16* gp = (u16*)Cout + (size_t)(m0 + row)*2048 + n0;
      gp[lane]      = f2bf(x_j  * cs - x_2j1 * sn);
      gp[64 + lane] = f2bf(x_j64 * cs + x_2j  * sn);
    }
  }
}

// fused Q/K/V projection, 1536 blocks (~5 resident/CU), natural block order (default
// round-robin already partitions B-columns across XCD L2s: r7 swizzle tripled FETCH).
// Q and K get the fused-RoPE epilogue; V gets the plain bf16 store.
__global__ __launch_bounds__(256) void gemm_qkv_kernel(
    const u16* __restrict__ A,
    const u16* __restrict__ WqT, const u16* __restrict__ WkT, const u16* __restrict__ WvT,
    const float* __restrict__ bq, const float* __restrict__ bk, const float* __restrict__ bv,
    u16* __restrict__ Qb, u16* __restrict__ Kb, u16* __restrict__ Vb){
  __shared__ u16 sm[16384];
  const int bx = blockIdx.x, by = blockIdx.y;
  const int mat = bx >> 4;                         // 0:Q 1:K 2:V
  const u16*   BT   = (mat==0)?WqT:(mat==1)?WkT:WvT;
  const float* bias = (mat==0)?bq :(mat==1)?bk :bv;
  u16*         Cout = (mat==0)?Qb :(mat==1)?Kb :Vb;
  if (mat < 2) gemm_tile<3>(A, BT, bias, Cout, by*128, (bx & 15)*128, sm);
  else         gemm_tile<0>(A, BT, bias, Cout, by*128, (bx & 15)*128, sm);
}

// Wo projection (fp32 out + bias), 512 blocks, natural order.
__global__ __launch_bounds__(256) void gemm_wo_kernel(const u16* __restrict__ A,
                                                      const u16* __restrict__ WoT,
                                                      const float* __restrict__ bias,
                                                      float* __restrict__ out){
  __shared__ u16 sm[16384];
  gemm_tile<1>(A, WoT, bias, out, blockIdx.y*128, blockIdx.x*128, sm);
}

// ---------------- transpose V: [B,S,H,D] -> VT [B,H,D,S] ----------------
__global__ __launch_bounds__(256) void tv_kernel(const u16* __restrict__ V, u16* __restrict__ VT){
  __shared__ u16 t[64*72];
  const int tb = blockIdx.x;                        // [0,2048): x=tb&31, y=(tb>>5)&1, z=tb>>6
  const int s0 = (tb & 31)*64;
  const int d0 = ((tb >> 5) & 1)*64;
  const int bh = tb >> 6;
  const int b = bh >> 4, h = bh & 15;
  const size_t obase = ((size_t)bh*128 + d0)*2048 + s0;
  const int tid = threadIdx.x;
  #pragma unroll
  for (int i=0;i<2;i++){
    int c = tid + i*256;
    int sl = c >> 3, dc = (c & 7) * 8;
    *(uint4*)(t + sl*72 + dc) =
      *(const uint4*)(V + ((size_t)(b*2048 + s0 + sl))*2048 + h*128 + d0 + dc);
  }
  __syncthreads();
  #pragma unroll
  for (int i=0;i<2;i++){
    int c = tid + i*256;
    int dl = c >> 3, sc4 = (c & 7) * 8;
    u16 tmp[8];
    #pragma unroll
    for (int j=0;j<8;j++) tmp[j] = t[(sc4+j)*72 + dl];
    *(uint4*)(VT + obase + (size_t)dl*2048 + sc4) = *(const uint4*)tmp;
  }
}

// ---------------- flash attention (r4-best): 4 waves, double-buffered K/V, in-reg softmax ----------------
// 32x32x16 MFMA. Q-tile 128 (4 waves x 32 q-rows), K-tile 64. LDS 64KB: 2 x {K [64][128] + V [128][64]},
// unpadded with 16B-block XOR swizzle (pos = blk ^ (row&7)).
// Swapped QK^T: S^T = mfma(A=K, B=Q); P^T frags via v_cvt_pk_bf16_f32 + permlane32_swap;
// O^T = mfma(A=V^T, B=P^T) -> lane-local 1/l normalization. Measured 104.6us (r4).
__global__ __launch_bounds__(256,2) void attn_kernel(const u16* __restrict__ Q,
                                                     const u16* __restrict__ K,
                                                     const u16* __restrict__ VT,
                                                     const int* __restrict__ mask,
                                                     u16* __restrict__ Out){
  constexpr int S = 2048;
  constexpr float SL2 = 0.08838834764831845f * 1.4426950408889634f;  // 1/sqrt(128) * log2(e)
  __shared__ u16 smem[32768];          // 64 KB: two 32KB buffers

  const int tid = threadIdx.x, w = tid >> 6, lane = tid & 63;
  const int qc = lane & 31;            // owned q-row; also key-row / d-row for A-frag reads
  const int h  = lane >> 5;            // k-slice half (A/B frag: k = 8*h + j)
  const int l7 = lane & 7;
  const int hh = blockIdx.y, b = blockIdx.z;
  const int q0 = blockIdx.x * 128;
  const size_t rowb = (size_t)b * 2048;
  const size_t bhD  = ((size_t)(b*16 + hh)) * 128;

  // Q fragments (B-operand: col = q = qc, k = d = 16t + 8h + j) straight from global (read once)
  s8v qf[8];
  {
    const u16* qp = Q + (rowb + q0 + w*32 + qc)*2048 + hh*128 + h*8;
    #pragma unroll
    for (int t=0;t<8;t++){ Frag f; f.u = *(const uint4*)(qp + t*16); qf[t] = f.s; }
  }

  f32x16 accO[4];                      // O^T: [d-block][16 regs]; row=d local, col=q=qc
  #pragma unroll
  for (int d=0; d<4; d++) accO[d] = (f32x16)0.f;
  float lsum = 0.f;

  const int sr4 = lane >> 4, sp16 = lane & 15;   // K staging: 4 rows x 16 blocks per instr
  const int vr8 = lane >> 3, vp8 = lane & 7;     // V staging: 8 rows x 8 blocks per instr

  // stage K tile [64][128] + V tile [128][64] for key block at key0 into buffer `base`
  auto stage = [&](u16* base, int key0){
    u16* Kd = base;
    u16* Vd = base + 8192;
    #pragma unroll
    for (int i=0;i<4;i++){
      int R = w*16 + i*4;
      int ob = sp16 ^ ((R&7) + sr4);              // (R+sr4)&7: R&7 in {0,4}, sr4<4
      async16(K + (rowb + key0 + R + sr4)*2048 + hh*128 + ob*8, Kd + R*128);
    }
    #pragma unroll
    for (int i=0;i<4;i++){
      int R = w*32 + i*8;
      int ob = vp8 ^ vr8;                         // (R&7)==0
      async16(VT + (bhD + R + vr8)*2048 + key0 + ob*8, Vd + R*64);
    }
  };

  // ---- prologue: stage tile 0, mask row 0 ----
  stage(smem, 0);
  int mv = mask[b*S + lane];
  __syncthreads();                                 // drains vmcnt -> buf0 ready
  unsigned long long bm = __ballot(mv != 0);
  int cur = 0;

  for (int it=0; it<32; ++it){
    // ---- issue next tile's loads before compute (2-phase pipeline) ----
    if (it < 31){
      stage(smem + (cur^1)*16384, (it+1)*64);
      mv = mask[b*S + (it+1)*64 + lane];
    }
    const u16* Ks = smem + cur*16384;              // [64 keys][128 d]
    const u16* Vs = Ks + 8192;                     // [128 d][64 keys]

    #pragma unroll
    for (int nb=0; nb<2; ++nb){
      // ---- S^T[key=nb*32+..][q] = K Q^T ----
      f32x16 sc = (f32x16)0.f;
      __builtin_amdgcn_s_setprio(1);
      #pragma unroll
      for (int t=0;t<8;t++){
        Frag kf; kf.u = *(const uint4*)(Ks + (nb*32 + qc)*128 + (((2*t + h) ^ l7)*8));
        sc = __builtin_amdgcn_mfma_f32_32x32x16_bf16(kf.s, qf[t], sc, 0, 0, 0);
      }
      __builtin_amdgcn_s_setprio(0);
      // ---- P = exp(score/sqrt(d)) (no-max softmax), lane-local row sum ----
      float p[16];
      #pragma unroll
      for (int m=0; m<16; ++m) p[m] = exp2f(sc[m] * SL2);
      if (bm != ~0ull){                            // wave-uniform fast path: mask all valid
        #pragma unroll
        for (int m=0; m<16; ++m){
          int bit = nb*32 + (m&3) + 8*(m>>2) + 4*h;
          if (!((bm >> bit) & 1ull)) p[m] = 0.f;
        }
      }
      #pragma unroll
      for (int m=0; m<16; ++m) lsum += p[m];

      // ---- build P^T B-frags in-register and do PV ----
      #pragma unroll
      for (int g=0; g<2; ++g){                     // 16-key sub-tile -> one frag
        u32 a0 = cvtpk(p[8*g+0], p[8*g+1]);        // keys 4h+{0,1}   (+16g local)
        u32 a1 = cvtpk(p[8*g+2], p[8*g+3]);        // keys 4h+{2,3}
        u32 a2 = cvtpk(p[8*g+4], p[8*g+5]);        // keys 8+4h+{0,1}
        u32 a3 = cvtpk(p[8*g+6], p[8*g+7]);        // keys 8+4h+{2,3}
        u32x2 r0 = __builtin_amdgcn_permlane32_swap(a0, a2, false, false);
        u32x2 r1 = __builtin_amdgcn_permlane32_swap(a1, a3, false, false);
        // frag elems j=0..7 = P[qc][16T + 8h + j]
        Frag pf; pf.u = make_uint4(r0[0], r1[0], r0[1], r1[1]);
        const int T = nb*2 + g;
        __builtin_amdgcn_s_setprio(1);
        #pragma unroll
        for (int d=0; d<4; ++d){
          Frag vf; vf.u = *(const uint4*)(Vs + (d*32 + qc)*64 + (((2*T + h) ^ l7)*8));
          accO[d] = __builtin_amdgcn_mfma_f32_32x32x16_bf16(vf.s, pf.s, accO[d], 0, 0, 0);
        }
        __builtin_amdgcn_s_setprio(0);
      }
    }
    __syncthreads();                               // all waves done with buf[cur]; buf[cur^1] staged
    bm = __ballot(mv != 0);
    cur ^= 1;
  }

  // ---- row sum across the two k-slice halves, normalize, store ----
  float sall = lsum + __shfl_xor(lsum, 32, 64);
  float invv = (sall > 0.f) ? 1.f/sall : 0.f;
  u16* orow = Out + (rowb + q0 + w*32 + qc)*2048 + hh*128;
  #pragma unroll
  for (int d=0; d<4; ++d){
    #pragma unroll
    for (int g2=0; g2<4; ++g2){
      uint2 o;
      o.x = cvtpk(accO[d][g2*4+0] * invv, accO[d][g2*4+1] * invv);
      o.y = cvtpk(accO[d][g2*4+2] * invv, accO[d][g2*4+3] * invv);
      *(uint2*)(orow + d*32 + g2*8 + 4*h) = o;     // d_local = (reg&3)+8*(reg>>2)+4h
    }
  }
}

extern "C" void kernel_launch(void* const* d_in, const int* in_sizes, int n_in,
                              void* d_out, int out_size, void* d_ws, size_t ws_size,
                              hipStream_t stream) {
  (void)in_sizes; (void)n_in; (void)out_size; (void)ws_size;
  const float* x    = (const float*)d_in[0];
  const int*   mask = (const int*)d_in[1];
  const float* Wq   = (const float*)d_in[2];
  const float* bq   = (const float*)d_in[3];
  const float* Wk   = (const float*)d_in[4];
  const float* bk   = (const float*)d_in[5];
  const float* Wv   = (const float*)d_in[6];
  const float* bv   = (const float*)d_in[7];
  const float* Wo   = (const float*)d_in[8];
  const float* bo   = (const float*)d_in[9];

  u16* xbf = (u16*)d_ws;                 // 8388608 elems
  u16* WqT = xbf + 8388608;              // 4194304 each
  u16* WkT = WqT + 4194304;
  u16* WvT = WkT + 4194304;
  u16* WoT = WvT + 4194304;
  u16* Qb  = WoT + 4194304;              // 8388608 each, [B,S,H,D] row-major
  u16* Kb  = Qb + 8388608;
  u16* Vb  = Kb + 8388608;
  u16* VTb = Vb + 8388608;               // V transposed [B,H,D,S]
  u16* Ab  = VTb + 8388608;              // attn out bf16 [B,S,E]

  prep_kernel<<<12288, 256, 0, stream>>>(x, xbf, Wq, Wk, Wv, Wo, WqT, WkT, WvT, WoT);
  gemm_qkv_kernel<<<dim3(48,32), 256, 0, stream>>>(xbf, WqT, WkT, WvT, bq, bk, bv, Qb, Kb, Vb);
  tv_kernel<<<2048, 256, 0, stream>>>(Vb, VTb);
  attn_kernel<<<dim3(16,16,2), 256, 0, stream>>>(Qb, Kb, VTb, mask, Ab);
  gemm_wo_kernel<<<dim3(16,32), 256, 0, stream>>>(Ab, WoT, bo, (float*)d_out);
}